// Round 9
// baseline (397.770 us; speedup 1.0000x reference)
//
#include <hip/hip_runtime.h>
#include <hip/hip_bf16.h>

#define DIN 128
#define HID1 128
#define HID2 64
#define OUTD 40

typedef __attribute__((ext_vector_type(8))) short bf16x8;
typedef __attribute__((ext_vector_type(4))) float f32x4;

__device__ __forceinline__ float bf2f(unsigned int u) {
    union { unsigned int i; float f; } c;
    c.i = u << 16;
    return c.f;
}
__device__ __forceinline__ unsigned short f2bf(float f) {
    union { float f; unsigned int i; } c; c.f = f;
    unsigned int r = c.i + 0x7FFFu + ((c.i >> 16) & 1u);   // RNE
    return (unsigned short)(r >> 16);
}
__device__ __forceinline__ unsigned int packbf(float lo, float hi) {
    return (unsigned int)f2bf(lo) | ((unsigned int)f2bf(hi) << 16);
}

// ---------------- dtype detect (block 0) + cnt zero (all blocks) ----------------
// flags[0] = 1 if float tensors are f32, 0 if bf16
// flags[1] = 1 if edge_index is int64, 0 if int32
__global__ void pre_kernel(const unsigned short* __restrict__ xu,
                           const int* __restrict__ ei, int* __restrict__ flags,
                           int* __restrict__ cnt, int N) {
    int i = blockIdx.x * blockDim.x + threadIdx.x;
    if (i < N) cnt[i] = 0;
    if (blockIdx.x == 0) {
        __shared__ int sh[2];
        if (threadIdx.x < 2) sh[threadIdx.x] = 0;
        __syncthreads();
        int bad = 0;
        for (int k = threadIdx.x; k < 2048; k += 256) {
            float v = bf2f(xu[2 * k]);
            float a = fabsf(v);
            if (!(a <= 1e4f) || (v != 0.f && a < 1e-4f)) bad++;
        }
        int zodd = 0;
        for (int k = threadIdx.x; k < 1024; k += 256)
            if (ei[2 * k + 1] == 0) zodd++;
        atomicAdd(&sh[0], bad);
        atomicAdd(&sh[1], zodd);
        __syncthreads();
        if (threadIdx.x == 0) {
            flags[0] = (sh[0] > 512) ? 1 : 0;
            flags[1] = (sh[1] > 512) ? 1 : 0;
        }
    }
}

__device__ __forceinline__ int get_src(const int* ei, int E, int e, int e64) {
    return e64 ? ei[2 * e] : ei[e];
}
__device__ __forceinline__ int get_dst(const int* ei, int E, int e, int e64) {
    return e64 ? ei[2 * (E + e)] : ei[E + e];
}

// THE single returned-atomic pass: pos[e] = rank of edge e within its dst bucket.
// Doubles as the degree histogram. 4 edges/thread for ILP.
__global__ void pos_kernel(const int* __restrict__ ei, int* __restrict__ cnt,
                           int* __restrict__ pos, int E, int N,
                           const int* __restrict__ flags) {
    int e64 = flags[1];
    int base = (blockIdx.x * blockDim.x + threadIdx.x) * 4;
    #pragma unroll
    for (int u = 0; u < 4; ++u) {
        int e = base + u;
        if (e < E) {
            int d = get_dst(ei, E, e, e64);
            pos[e] = ((unsigned)d < (unsigned)N) ? atomicAdd(&cnt[d], 1) : -1;
        }
    }
}

// ---- 3-stage device-wide exclusive scan of cnt -> indptr (+dinv) ----

__launch_bounds__(256)
__global__ void bsum_kernel(const int* __restrict__ cnt, int* __restrict__ bsum, int N) {
    __shared__ int sh[256];
    int t = threadIdx.x;
    int i = blockIdx.x * 256 + t;
    sh[t] = (i < N) ? cnt[i] : 0;
    __syncthreads();
    #pragma unroll
    for (int off = 128; off >= 1; off >>= 1) {
        if (t < off) sh[t] += sh[t + off];
        __syncthreads();
    }
    if (t == 0) bsum[blockIdx.x] = sh[0];
}

__launch_bounds__(256)
__global__ void bscan_kernel(const int* __restrict__ bsum, int* __restrict__ bbase,
                             int* __restrict__ indptr, int NB, int N) {
    __shared__ int part[256];
    int t = threadIdx.x;
    int CH = (NB + 255) / 256;
    int lo = t * CH, hi = lo + CH; if (hi > NB) hi = NB;
    int s = 0;
    for (int i = lo; i < hi; ++i) s += bsum[i];
    part[t] = s;
    __syncthreads();
    for (int off = 1; off < 256; off <<= 1) {
        int v = (t >= off) ? part[t - off] : 0;
        __syncthreads();
        part[t] += v;
        __syncthreads();
    }
    int run = (t > 0) ? part[t - 1] : 0;
    for (int i = lo; i < hi; ++i) { bbase[i] = run; run += bsum[i]; }
    if (t == 255) indptr[N] = part[255];
}

__launch_bounds__(256)
__global__ void emit_kernel(const int* __restrict__ cnt, const int* __restrict__ bbase,
                            int* __restrict__ indptr, float* __restrict__ dinv, int N) {
    __shared__ int sh[256];
    int t = threadIdx.x;
    int i = blockIdx.x * 256 + t;
    int c = (i < N) ? cnt[i] : 0;
    sh[t] = c;
    __syncthreads();
    for (int off = 1; off < 256; off <<= 1) {
        int v = (t >= off) ? sh[t - off] : 0;
        __syncthreads();
        sh[t] += v;
        __syncthreads();
    }
    if (i < N) {
        int excl = sh[t] - c + bbase[blockIdx.x];
        indptr[i] = excl;
        dinv[i] = 1.0f / sqrtf((float)(c + 1));   // +1 self loop
    }
}

// atomic-free scatter: slot = indptr[dst] + pos[e]; also precomputes the edge
// norm dinv[src]*dinv[dst] so the 3 agg passes never touch dinv per-edge.
__global__ void scatter_kernel(const int* __restrict__ ei, const int* __restrict__ indptr,
                               const int* __restrict__ pos, const float* __restrict__ dinv,
                               int2* __restrict__ csr_sn,
                               int E, int N, const int* __restrict__ flags) {
    int e64 = flags[1];
    int base = (blockIdx.x * blockDim.x + threadIdx.x) * 4;
    #pragma unroll
    for (int u = 0; u < 4; ++u) {
        int e = base + u;
        if (e < E) {
            int p = pos[e];
            if (p >= 0) {
                int d = get_dst(ei, E, e, e64);
                int s = get_src(ei, E, e, e64);
                if ((unsigned)s >= (unsigned)N) s = 0;
                float nrm = dinv[s] * dinv[d];
                csr_sn[indptr[d] + p] = make_int2(s, __float_as_int(nrm));
            }
        }
    }
}

// ---------------- weight conversion into f32 / bf16 arenas ----------------
// tobf=1: bf16 arena TRANSPOSED (W1/W2/W3).  tobf=0: f32 arena.
// tobf=3: x -> bf16 straight copy into dst3, only when x is f32.

struct WCvt {
    const void* p[15];
    int sz[15];
    int off[15];
    int tobf[15];
    int cols[15];
};

__global__ void wcvt_kernel(WCvt w, unsigned short* __restrict__ wbf,
                            float* __restrict__ wf, unsigned short* __restrict__ dst3,
                            const int* __restrict__ flags) {
    int xf32 = flags[0];
    int stride = gridDim.x * blockDim.x;
    int tid = blockIdx.x * blockDim.x + threadIdx.x;
    for (int a = 0; a < 15; ++a) {
        int tobf = w.tobf[a];
        if (tobf == 3 && !xf32) continue;        // x already bf16: mm1 reads it directly
        const float* pf = (const float*)w.p[a];
        const unsigned short* pb = (const unsigned short*)w.p[a];
        int n = w.sz[a], off = w.off[a];
        int cols = w.cols[a];
        int rows = (tobf == 1) ? (n / cols) : 0;
        for (int i = tid; i < n; i += stride) {
            float v = xf32 ? pf[i] : bf2f(pb[i]);
            if (tobf == 1) {
                int k = i / cols, m = i % cols;
                wbf[off + m * rows + k] = f2bf(v);   // transposed
            } else if (tobf == 3) {
                dst3[i] = f2bf(v);
            } else {
                wf[off + i] = v;
            }
        }
    }
}

// ---------------- MFMA matmul: C[N,M](bf16) = A[N,K](bf16) x W[K,M](bf16) ----------------

template<int K, int M>
__launch_bounds__(256)
__global__ void mm_mfma_kernel(const unsigned short* __restrict__ A0,
                               const unsigned short* __restrict__ A1,
                               const unsigned short* __restrict__ WT,
                               unsigned short* __restrict__ C, int N,
                               const int* __restrict__ flags, int useAlt) {
    __shared__ unsigned short Ws[M][K + 8];
    const unsigned short* A = (useAlt && flags[0]) ? A1 : A0;
    int tid = threadIdx.x;
    for (int idx = tid; idx < M * K / 8; idx += 256) {
        int r = idx / (K / 8), c8 = idx % (K / 8);
        *(uint4*)&Ws[r][c8 * 8] = *(const uint4*)&WT[r * K + c8 * 8];
    }
    __syncthreads();
    int w = tid >> 6, lane = tid & 63;
    int m = lane & 15, q = lane >> 4;
    int row_a = blockIdx.x * 64 + w * 16 + m;
    if (row_a >= N) row_a = N - 1;              // clamp; garbage rows masked at store
    const unsigned short* arow = A + (size_t)row_a * K;
    f32x4 acc[M / 16];
    #pragma unroll
    for (int t = 0; t < M / 16; ++t) acc[t] = (f32x4){0.f, 0.f, 0.f, 0.f};
    #pragma unroll
    for (int ks = 0; ks < K / 32; ++ks) {
        int k0 = ks * 32 + q * 8;
        bf16x8 a = *(const bf16x8*)&arow[k0];
        #pragma unroll
        for (int t = 0; t < M / 16; ++t) {
            bf16x8 b = *(const bf16x8*)&Ws[t * 16 + m][k0];
            acc[t] = __builtin_amdgcn_mfma_f32_16x16x32_bf16(a, b, acc[t], 0, 0, 0);
        }
    }
    int rbase = blockIdx.x * 64 + w * 16 + q * 4;
    #pragma unroll
    for (int reg = 0; reg < 4; ++reg) {
        int row = rbase + reg;
        if (row < N) {
            #pragma unroll
            for (int t = 0; t < M / 16; ++t)
                C[(size_t)row * M + t * 16 + m] = f2bf(acc[t][reg]);
        }
    }
}

// ---------------- aggregation + optional ReLU/LN ----------------
// 4 NODES PER WAVE: wave = 4 independent 16-lane groups, one node each.
// Group lanes cover the full row (16 x VPL = H); each group streams its own
// edges with unroll-4 (4 outstanding uint4 gathers/lane, 16/wave). The 4
// per-node serial chains (indptr/dinv/self/staging/LN) ILP-overlap in-wave.
// No cross-group reduction: LN shuffles (xor<=8) stay inside the group.
// csr_sn[slot] = {src, dinv[src]*dinv[dst]} precomputed by scatter.

template<int VPL>
__device__ __forceinline__ void gacc1(float* acc, const unsigned short* r, float n) {
    if constexpr (VPL == 8) {
        uint4 u = *(const uint4*)r;
        acc[0] += bf2f(u.x & 0xffffu) * n; acc[1] += bf2f(u.x >> 16) * n;
        acc[2] += bf2f(u.y & 0xffffu) * n; acc[3] += bf2f(u.y >> 16) * n;
        acc[4] += bf2f(u.z & 0xffffu) * n; acc[5] += bf2f(u.z >> 16) * n;
        acc[6] += bf2f(u.w & 0xffffu) * n; acc[7] += bf2f(u.w >> 16) * n;
    } else {
        uint2 u = *(const uint2*)r;
        acc[0] += bf2f(u.x & 0xffffu) * n; acc[1] += bf2f(u.x >> 16) * n;
        acc[2] += bf2f(u.y & 0xffffu) * n; acc[3] += bf2f(u.y >> 16) * n;
    }
}

template<int VPL>
__device__ __forceinline__ void gacc4(float* acc,
                                      const unsigned short* r0, float n0,
                                      const unsigned short* r1, float n1,
                                      const unsigned short* r2, float n2,
                                      const unsigned short* r3, float n3) {
    if constexpr (VPL == 8) {
        uint4 u0 = *(const uint4*)r0;
        uint4 u1 = *(const uint4*)r1;
        uint4 u2 = *(const uint4*)r2;
        uint4 u3 = *(const uint4*)r3;
        acc[0] += bf2f(u0.x & 0xffffu) * n0 + bf2f(u1.x & 0xffffu) * n1
                + bf2f(u2.x & 0xffffu) * n2 + bf2f(u3.x & 0xffffu) * n3;
        acc[1] += bf2f(u0.x >> 16) * n0 + bf2f(u1.x >> 16) * n1
                + bf2f(u2.x >> 16) * n2 + bf2f(u3.x >> 16) * n3;
        acc[2] += bf2f(u0.y & 0xffffu) * n0 + bf2f(u1.y & 0xffffu) * n1
                + bf2f(u2.y & 0xffffu) * n2 + bf2f(u3.y & 0xffffu) * n3;
        acc[3] += bf2f(u0.y >> 16) * n0 + bf2f(u1.y >> 16) * n1
                + bf2f(u2.y >> 16) * n2 + bf2f(u3.y >> 16) * n3;
        acc[4] += bf2f(u0.z & 0xffffu) * n0 + bf2f(u1.z & 0xffffu) * n1
                + bf2f(u2.z & 0xffffu) * n2 + bf2f(u3.z & 0xffffu) * n3;
        acc[5] += bf2f(u0.z >> 16) * n0 + bf2f(u1.z >> 16) * n1
                + bf2f(u2.z >> 16) * n2 + bf2f(u3.z >> 16) * n3;
        acc[6] += bf2f(u0.w & 0xffffu) * n0 + bf2f(u1.w & 0xffffu) * n1
                + bf2f(u2.w & 0xffffu) * n2 + bf2f(u3.w & 0xffffu) * n3;
        acc[7] += bf2f(u0.w >> 16) * n0 + bf2f(u1.w >> 16) * n1
                + bf2f(u2.w >> 16) * n2 + bf2f(u3.w >> 16) * n3;
    } else {
        uint2 u0 = *(const uint2*)r0;
        uint2 u1 = *(const uint2*)r1;
        uint2 u2 = *(const uint2*)r2;
        uint2 u3 = *(const uint2*)r3;
        acc[0] += bf2f(u0.x & 0xffffu) * n0 + bf2f(u1.x & 0xffffu) * n1
                + bf2f(u2.x & 0xffffu) * n2 + bf2f(u3.x & 0xffffu) * n3;
        acc[1] += bf2f(u0.x >> 16) * n0 + bf2f(u1.x >> 16) * n1
                + bf2f(u2.x >> 16) * n2 + bf2f(u3.x >> 16) * n3;
        acc[2] += bf2f(u0.y & 0xffffu) * n0 + bf2f(u1.y & 0xffffu) * n1
                + bf2f(u2.y & 0xffffu) * n2 + bf2f(u3.y & 0xffffu) * n3;
        acc[3] += bf2f(u0.y >> 16) * n0 + bf2f(u1.y >> 16) * n1
                + bf2f(u2.y >> 16) * n2 + bf2f(u3.y >> 16) * n3;
    }
}

template<int H, bool RELU_LN, bool EMB>
__launch_bounds__(256)
__global__ void agg_kernel(const unsigned short* __restrict__ h,
                           const int* __restrict__ indptr,
                           const int2* __restrict__ csr_sn,
                           const float* __restrict__ dinv,
                           const float* __restrict__ bias,
                           const float* __restrict__ gamma,
                           const float* __restrict__ beta,
                           unsigned short* __restrict__ out,
                           void* __restrict__ out_emb,
                           int N, const int* __restrict__ flags) {
    constexpr int VPL = H / 16;                 // 8 (H=128), 4 (H=64)
    __shared__ int2 lsn[4][4][16];              // [wave][group][idx]
    int w = threadIdx.x >> 6;
    int lane = threadIdx.x & 63;
    int g = lane >> 4;                          // group = node within wave
    int idx = lane & 15;
    int node = blockIdx.x * 16 + w * 4 + g;
    bool active = node < N;
    int nd = active ? node : N - 1;             // clamp; inactive groups never store
    float di = dinv[nd];
    int c0 = idx * VPL;
    float acc[VPL];
    #pragma unroll
    for (int v = 0; v < VPL; ++v) acc[v] = 0.f;
    // self loop (full group covers the row once)
    gacc1<VPL>(acc, h + (size_t)nd * H + c0, di * di);
    int beg = indptr[nd], end = indptr[nd + 1];
    for (int base = beg; base < end; base += 16) {
        int m = end - base; if (m > 16) m = 16;
        if (idx < m) lsn[w][g][idx] = csr_sn[base + idx];
        // same-wave LDS write->read: ordered, no barrier
        int j = 0;
        for (; j + 3 < m; j += 4) {
            int2 e0 = lsn[w][g][j],     e1 = lsn[w][g][j + 1];
            int2 e2 = lsn[w][g][j + 2], e3 = lsn[w][g][j + 3];
            gacc4<VPL>(acc,
                       h + (size_t)e0.x * H + c0, __int_as_float(e0.y),
                       h + (size_t)e1.x * H + c0, __int_as_float(e1.y),
                       h + (size_t)e2.x * H + c0, __int_as_float(e2.y),
                       h + (size_t)e3.x * H + c0, __int_as_float(e3.y));
        }
        for (; j < m; ++j) {
            int2 e = lsn[w][g][j];
            gacc1<VPL>(acc, h + (size_t)e.x * H + c0, __int_as_float(e.y));
        }
    }
    #pragma unroll
    for (int v = 0; v < VPL; ++v) acc[v] += bias[c0 + v];
    if constexpr (RELU_LN) {
        #pragma unroll
        for (int v = 0; v < VPL; ++v) acc[v] = fmaxf(acc[v], 0.f);
        float s = 0.f, sq = 0.f;
        #pragma unroll
        for (int v = 0; v < VPL; ++v) { s += acc[v]; sq += acc[v] * acc[v]; }
        #pragma unroll
        for (int off = 8; off >= 1; off >>= 1) {   // stays inside the 16-lane group
            s += __shfl_xor(s, off, 64);
            sq += __shfl_xor(sq, off, 64);
        }
        float mu = s * (1.0f / H);
        float var = fmaxf(sq * (1.0f / H) - mu * mu, 0.f);
        float inv = 1.0f / sqrtf(var + 1e-5f);
        #pragma unroll
        for (int v = 0; v < VPL; ++v)
            acc[v] = (acc[v] - mu) * inv * gamma[c0 + v] + beta[c0 + v];
    }
    if (active) {
        unsigned short* orow = out + (size_t)node * H + c0;
        if constexpr (VPL == 8) {
            uint4 p;
            p.x = packbf(acc[0], acc[1]); p.y = packbf(acc[2], acc[3]);
            p.z = packbf(acc[4], acc[5]); p.w = packbf(acc[6], acc[7]);
            *(uint4*)orow = p;
        } else {
            uint2 p; p.x = packbf(acc[0], acc[1]); p.y = packbf(acc[2], acc[3]);
            *(uint2*)orow = p;
        }
        if constexpr (EMB) {
            if (flags[0]) {
                float* o = (float*)out_emb + (size_t)node * H + c0;
                #pragma unroll
                for (int v4 = 0; v4 < VPL / 4; ++v4)
                    *(float4*)(o + v4 * 4) = make_float4(acc[v4 * 4], acc[v4 * 4 + 1],
                                                         acc[v4 * 4 + 2], acc[v4 * 4 + 3]);
            } else {
                unsigned short* o = (unsigned short*)out_emb + (size_t)node * H + c0;
                #pragma unroll
                for (int v2 = 0; v2 < VPL / 2; ++v2)
                    ((unsigned int*)o)[v2] = packbf(acc[v2 * 2], acc[v2 * 2 + 1]);
            }
        }
    }
}

// ---------------- post-mp head: LDS-tiled GEMM + log_softmax ----------------

__launch_bounds__(256)
__global__ void head_kernel(const unsigned short* __restrict__ emb,
                            const float* __restrict__ Wp1,
                            const float* __restrict__ bp1,
                            const float* __restrict__ Wp2,
                            const float* __restrict__ bp2,
                            void* __restrict__ d_out, int N,
                            const int* __restrict__ flags) {
    __shared__ float Est[64][68];     // [k][row], relu'd
    __shared__ float W1s[64][64];     // [k][c]
    __shared__ float Tst[64][68];     // [c][row]
    __shared__ float W2s[64][OUTD];   // [c][o]
    __shared__ float b1s[64];
    __shared__ float b2s[OUTD];
    int tid = threadIdx.x;
    int row0 = blockIdx.x * 64;
    for (int i = tid; i < 64 * 64; i += 256) W1s[i >> 6][i & 63] = Wp1[i];
    for (int i = tid; i < 64 * OUTD; i += 256) W2s[i / OUTD][i % OUTD] = Wp2[i];
    if (tid < 64) b1s[tid] = bp1[tid];
    if (tid < OUTD) b2s[tid] = bp2[tid];
    for (int i = tid; i < 64 * 32; i += 256) {
        int r = i >> 5, kk = i & 31;
        int row = row0 + r;
        unsigned int u = (row < N) ? *(const unsigned int*)&emb[(size_t)row * 64 + kk * 2] : 0u;
        Est[kk * 2][r]     = fmaxf(bf2f(u & 0xffffu), 0.f);
        Est[kk * 2 + 1][r] = fmaxf(bf2f(u >> 16), 0.f);
    }
    __syncthreads();
    // phase 1
    {
        int rg = tid >> 4, cg = tid & 15;
        int r = rg * 4, c = cg * 4;
        float acc[4][4];
        #pragma unroll
        for (int i = 0; i < 4; ++i)
            #pragma unroll
            for (int jj = 0; jj < 4; ++jj) acc[i][jj] = b1s[c + jj];
        #pragma unroll 4
        for (int k = 0; k < 64; ++k) {
            float4 a = *(const float4*)&Est[k][r];
            float4 wv = *(const float4*)&W1s[k][c];
            acc[0][0] += a.x * wv.x; acc[0][1] += a.x * wv.y; acc[0][2] += a.x * wv.z; acc[0][3] += a.x * wv.w;
            acc[1][0] += a.y * wv.x; acc[1][1] += a.y * wv.y; acc[1][2] += a.y * wv.z; acc[1][3] += a.y * wv.w;
            acc[2][0] += a.z * wv.x; acc[2][1] += a.z * wv.y; acc[2][2] += a.z * wv.z; acc[2][3] += a.z * wv.w;
            acc[3][0] += a.w * wv.x; acc[3][1] += a.w * wv.y; acc[3][2] += a.w * wv.z; acc[3][3] += a.w * wv.w;
        }
        #pragma unroll
        for (int i = 0; i < 4; ++i)
            #pragma unroll
            for (int jj = 0; jj < 4; ++jj) Tst[c + jj][r + i] = acc[i][jj];
    }
    __syncthreads();
    // phase 2 + 3
    int row = tid >> 2, tc = tid & 3, o0 = tc * 10;
    int node = row0 + row;
    float u[10];
    #pragma unroll
    for (int o = 0; o < 10; ++o) u[o] = b2s[o0 + o];
    for (int c2 = 0; c2 < 64; ++c2) {
        float tv = Tst[c2][row];
        const float2* wp = (const float2*)&W2s[c2][o0];
        #pragma unroll
        for (int o2 = 0; o2 < 5; ++o2) {
            float2 wv = wp[o2];
            u[o2 * 2]     += tv * wv.x;
            u[o2 * 2 + 1] += tv * wv.y;
        }
    }
    float mx = u[0];
    #pragma unroll
    for (int o = 1; o < 10; ++o) mx = fmaxf(mx, u[o]);
    mx = fmaxf(mx, __shfl_xor(mx, 1, 64));
    mx = fmaxf(mx, __shfl_xor(mx, 2, 64));
    float sum = 0.f;
    #pragma unroll
    for (int o = 0; o < 10; ++o) sum += __expf(u[o] - mx);
    sum += __shfl_xor(sum, 1, 64);
    sum += __shfl_xor(sum, 2, 64);
    float lse = mx + __logf(sum);
    if (node < N) {
        if (flags[0]) {
            float* base = (float*)d_out + (size_t)N * HID2;
            float* op = base + (size_t)node * OUTD + o0;
            #pragma unroll
            for (int o = 0; o < 10; ++o) op[o] = u[o] - lse;
        } else {
            unsigned short* base = (unsigned short*)d_out + (size_t)N * HID2;
            unsigned int* op = (unsigned int*)(base + (size_t)node * OUTD + o0);
            #pragma unroll
            for (int o2 = 0; o2 < 5; ++o2)
                op[o2] = packbf(u[o2 * 2] - lse, u[o2 * 2 + 1] - lse);
        }
    }
}

// ---------------- launch ----------------

extern "C" void kernel_launch(void* const* d_in, const int* in_sizes, int n_in,
                              void* d_out, int out_size, void* d_ws, size_t ws_size,
                              hipStream_t stream) {
    const unsigned short* xu = (const unsigned short*)d_in[0];
    const int*            ei = (const int*)d_in[1];

    const int N = in_sizes[0] / DIN;   // 50000
    const int E = in_sizes[1] / 2;     // 800000

    size_t off = 0;
    auto take = [&](size_t bytes) {
        size_t cur = off;
        off += (bytes + 255) & ~(size_t)255;
        return cur;
    };
    char* ws = (char*)d_ws;
    int*   flags   = (int*)  (ws + take(256));
    int*   cnt     = (int*)  (ws + take((size_t)N * 4));
    float* dinv    = (float*)(ws + take((size_t)N * 4));
    int*   indptr  = (int*)  (ws + take((size_t)(N + 1) * 4));
    int*   pos     = (int*)  (ws + take((size_t)E * 4));
    int2*  csr_sn  = (int2*) (ws + take((size_t)E * 8));
    int*   bsum    = (int*)  (ws + take(((size_t)N / 256 + 2) * 4));
    int*   bbase   = (int*)  (ws + take(((size_t)N / 256 + 2) * 4));
    unsigned short* wbf = (unsigned short*)(ws + take(32768 * 2));
    float*          wf  = (float*)         (ws + take(8192 * 4));
    unsigned short* hbuf = (unsigned short*)(ws + take((size_t)N * DIN * 2));
    unsigned short* abuf = (unsigned short*)(ws + take((size_t)N * DIN * 2));
    (void)ws_size; (void)n_in; (void)out_size;

    const int TB = 256;
    dim3 blk(TB);
    const int NB = (N + 255) / 256;

    pre_kernel<<<dim3(NB), blk, 0, stream>>>(xu, ei, flags, cnt, N);
    pos_kernel<<<dim3((E + 1023) / 1024), blk, 0, stream>>>(ei, cnt, pos, E, N, flags);
    bsum_kernel<<<dim3(NB), blk, 0, stream>>>(cnt, bsum, N);
    bscan_kernel<<<dim3(1), blk, 0, stream>>>(bsum, bbase, indptr, NB, N);
    emit_kernel<<<dim3(NB), blk, 0, stream>>>(cnt, bbase, indptr, dinv, N);
    scatter_kernel<<<dim3((E + 1023) / 1024), blk, 0, stream>>>(ei, indptr, pos, dinv, csr_sn, E, N, flags);

    // weight conversion: W1/W2/W3 -> bf16 arena TRANSPOSED; rest -> f32 arena;
    // entry 14 = x -> abuf bf16 (only when x is f32)
    WCvt w;
    int bfoff = 0, foff = 0;
    int offs[14];
    const int wcols[14] = {HID1, 0, HID2, 0, HID2, 0, 0, 0, 0, 0, 0, 0, 0, 0};
    for (int a = 0; a < 14; ++a) {
        int idx = a + 2;
        w.p[a] = d_in[idx];
        w.sz[a] = in_sizes[idx];
        int tobf = (idx == 2 || idx == 4 || idx == 6) ? 1 : 0;
        w.tobf[a] = tobf;
        w.cols[a] = tobf ? wcols[a] : 1;
        if (tobf) { w.off[a] = bfoff; bfoff += in_sizes[idx]; }
        else      { w.off[a] = foff;  foff  += in_sizes[idx]; }
        offs[a] = w.off[a];
    }
    w.p[14] = d_in[0]; w.sz[14] = N * DIN; w.off[14] = 0; w.tobf[14] = 3; w.cols[14] = 1;
    wcvt_kernel<<<dim3(128), blk, 0, stream>>>(w, wbf, wf, abuf, flags);

    unsigned short* W1t = wbf + offs[0];   // [128][128] transposed
    unsigned short* W2t = wbf + offs[2];   // [64][128] transposed
    unsigned short* W3t = wbf + offs[4];   // [64][64] transposed
    float* b1f  = wf + offs[1];
    float* b2f  = wf + offs[3];
    float* b3f  = wf + offs[5];
    float* g1f  = wf + offs[6];
    float* be1f = wf + offs[7];
    float* g2f  = wf + offs[8];
    float* be2f = wf + offs[9];
    float* Wp1f = wf + offs[10];
    float* bp1f = wf + offs[11];
    float* Wp2f = wf + offs[12];
    float* bp2f = wf + offs[13];

    const int MMG = (N + 63) / 64;
    const int AGG = (N + 15) / 16;

    // layer 1
    mm_mfma_kernel<DIN, HID1><<<dim3(MMG), blk, 0, stream>>>(xu, abuf, W1t, hbuf, N, flags, 1);
    agg_kernel<HID1, true, false><<<dim3(AGG), blk, 0, stream>>>(
        hbuf, indptr, csr_sn, dinv, b1f, g1f, be1f, abuf, nullptr, N, flags);

    // layer 2
    mm_mfma_kernel<HID1, HID2><<<dim3(MMG), blk, 0, stream>>>(abuf, nullptr, W2t, hbuf, N, flags, 0);
    agg_kernel<HID2, true, false><<<dim3(AGG), blk, 0, stream>>>(
        hbuf, indptr, csr_sn, dinv, b2f, g2f, be2f, abuf, nullptr, N, flags);

    // layer 3 -> emb
    mm_mfma_kernel<HID2, HID2><<<dim3(MMG), blk, 0, stream>>>(abuf, nullptr, W3t, hbuf, N, flags, 0);
    agg_kernel<HID2, false, true><<<dim3(AGG), blk, 0, stream>>>(
        hbuf, indptr, csr_sn, dinv, b3f, nullptr, nullptr, abuf, d_out, N, flags);

    // head
    head_kernel<<<dim3((N + 63) / 64), blk, 0, stream>>>(
        abuf, Wp1f, bp1f, Wp2f, bp2f, d_out, N, flags);
}

// Round 10
// 312.809 us; speedup vs baseline: 1.2716x; 1.2716x over previous
//
#include <hip/hip_runtime.h>
#include <hip/hip_bf16.h>

#define DIN 128
#define HID1 128
#define HID2 64
#define OUTD 40

typedef __attribute__((ext_vector_type(8))) short bf16x8;
typedef __attribute__((ext_vector_type(4))) float f32x4;

__device__ __forceinline__ float bf2f(unsigned int u) {
    union { unsigned int i; float f; } c;
    c.i = u << 16;
    return c.f;
}
__device__ __forceinline__ unsigned short f2bf(float f) {
    union { float f; unsigned int i; } c; c.f = f;
    unsigned int r = c.i + 0x7FFFu + ((c.i >> 16) & 1u);   // RNE
    return (unsigned short)(r >> 16);
}
__device__ __forceinline__ unsigned int packbf(float lo, float hi) {
    return (unsigned int)f2bf(lo) | ((unsigned int)f2bf(hi) << 16);
}

// ---------------- dtype detect (block 0) + cnt zero (all blocks) ----------------
// flags[0] = 1 if float tensors are f32, 0 if bf16   [measured r9: =1 on this dataset]
// flags[1] = 1 if edge_index is int64, 0 if int32
__global__ void pre_kernel(const unsigned short* __restrict__ xu,
                           const int* __restrict__ ei, int* __restrict__ flags,
                           int* __restrict__ cnt, int N) {
    int i = blockIdx.x * blockDim.x + threadIdx.x;
    if (i < N) cnt[i] = 0;
    if (blockIdx.x == 0) {
        __shared__ int sh[2];
        if (threadIdx.x < 2) sh[threadIdx.x] = 0;
        __syncthreads();
        int bad = 0;
        for (int k = threadIdx.x; k < 2048; k += 256) {
            float v = bf2f(xu[2 * k]);
            float a = fabsf(v);
            if (!(a <= 1e4f) || (v != 0.f && a < 1e-4f)) bad++;
        }
        int zodd = 0;
        for (int k = threadIdx.x; k < 1024; k += 256)
            if (ei[2 * k + 1] == 0) zodd++;
        atomicAdd(&sh[0], bad);
        atomicAdd(&sh[1], zodd);
        __syncthreads();
        if (threadIdx.x == 0) {
            flags[0] = (sh[0] > 512) ? 1 : 0;
            flags[1] = (sh[1] > 512) ? 1 : 0;
        }
    }
}

__device__ __forceinline__ int get_src(const int* ei, int E, int e, int e64) {
    return e64 ? ei[2 * e] : ei[e];
}
__device__ __forceinline__ int get_dst(const int* ei, int E, int e, int e64) {
    return e64 ? ei[2 * (E + e)] : ei[E + e];
}

// THE single returned-atomic pass: pos[e] = rank of edge e within its dst bucket.
__global__ void pos_kernel(const int* __restrict__ ei, int* __restrict__ cnt,
                           int* __restrict__ pos, int E, int N,
                           const int* __restrict__ flags) {
    int e64 = flags[1];
    int base = (blockIdx.x * blockDim.x + threadIdx.x) * 4;
    #pragma unroll
    for (int u = 0; u < 4; ++u) {
        int e = base + u;
        if (e < E) {
            int d = get_dst(ei, E, e, e64);
            pos[e] = ((unsigned)d < (unsigned)N) ? atomicAdd(&cnt[d], 1) : -1;
        }
    }
}

// ---- 3-stage device-wide exclusive scan of cnt -> indptr (+dinv) ----

__launch_bounds__(256)
__global__ void bsum_kernel(const int* __restrict__ cnt, int* __restrict__ bsum, int N) {
    __shared__ int sh[256];
    int t = threadIdx.x;
    int i = blockIdx.x * 256 + t;
    sh[t] = (i < N) ? cnt[i] : 0;
    __syncthreads();
    #pragma unroll
    for (int off = 128; off >= 1; off >>= 1) {
        if (t < off) sh[t] += sh[t + off];
        __syncthreads();
    }
    if (t == 0) bsum[blockIdx.x] = sh[0];
}

__launch_bounds__(256)
__global__ void bscan_kernel(const int* __restrict__ bsum, int* __restrict__ bbase,
                             int* __restrict__ indptr, int NB, int N) {
    __shared__ int part[256];
    int t = threadIdx.x;
    int CH = (NB + 255) / 256;
    int lo = t * CH, hi = lo + CH; if (hi > NB) hi = NB;
    int s = 0;
    for (int i = lo; i < hi; ++i) s += bsum[i];
    part[t] = s;
    __syncthreads();
    for (int off = 1; off < 256; off <<= 1) {
        int v = (t >= off) ? part[t - off] : 0;
        __syncthreads();
        part[t] += v;
        __syncthreads();
    }
    int run = (t > 0) ? part[t - 1] : 0;
    for (int i = lo; i < hi; ++i) { bbase[i] = run; run += bsum[i]; }
    if (t == 255) indptr[N] = part[255];
}

__launch_bounds__(256)
__global__ void emit_kernel(const int* __restrict__ cnt, const int* __restrict__ bbase,
                            int* __restrict__ indptr, float* __restrict__ dinv, int N) {
    __shared__ int sh[256];
    int t = threadIdx.x;
    int i = blockIdx.x * 256 + t;
    int c = (i < N) ? cnt[i] : 0;
    sh[t] = c;
    __syncthreads();
    for (int off = 1; off < 256; off <<= 1) {
        int v = (t >= off) ? sh[t - off] : 0;
        __syncthreads();
        sh[t] += v;
        __syncthreads();
    }
    if (i < N) {
        int excl = sh[t] - c + bbase[blockIdx.x];
        indptr[i] = excl;
        dinv[i] = 1.0f / sqrtf((float)(c + 1));   // +1 self loop
    }
}

// atomic-free scatter: slot = indptr[dst] + pos[e]; precomputes edge norm.
__global__ void scatter_kernel(const int* __restrict__ ei, const int* __restrict__ indptr,
                               const int* __restrict__ pos, const float* __restrict__ dinv,
                               int2* __restrict__ csr_sn,
                               int E, int N, const int* __restrict__ flags) {
    int e64 = flags[1];
    int base = (blockIdx.x * blockDim.x + threadIdx.x) * 4;
    #pragma unroll
    for (int u = 0; u < 4; ++u) {
        int e = base + u;
        if (e < E) {
            int p = pos[e];
            if (p >= 0) {
                int d = get_dst(ei, E, e, e64);
                int s = get_src(ei, E, e, e64);
                if ((unsigned)s >= (unsigned)N) s = 0;
                float nrm = dinv[s] * dinv[d];
                csr_sn[indptr[d] + p] = make_int2(s, __float_as_int(nrm));
            }
        }
    }
}

// ---------------- weight conversion into f32 / bf16 arenas (weights only) ----------------
// tobf=1: bf16 arena TRANSPOSED (W1/W2/W3).  tobf=0: f32 arena.

struct WCvt {
    const void* p[14];
    int sz[14];
    int off[14];
    int tobf[14];
    int cols[14];
};

__global__ void wcvt_kernel(WCvt w, unsigned short* __restrict__ wbf,
                            float* __restrict__ wf, const int* __restrict__ flags) {
    int xf32 = flags[0];
    int stride = gridDim.x * blockDim.x;
    int tid = blockIdx.x * blockDim.x + threadIdx.x;
    for (int a = 0; a < 14; ++a) {
        const float* pf = (const float*)w.p[a];
        const unsigned short* pb = (const unsigned short*)w.p[a];
        int n = w.sz[a], off = w.off[a], tobf = w.tobf[a];
        int cols = w.cols[a];
        int rows = tobf ? (n / cols) : 0;
        for (int i = tid; i < n; i += stride) {
            float v = xf32 ? pf[i] : bf2f(pb[i]);
            if (tobf) {
                int k = i / cols, m = i % cols;
                wbf[off + m * rows + k] = f2bf(v);   // transposed
            } else {
                wf[off + i] = v;
            }
        }
    }
}

// ---------------- MFMA matmul: C[N,M](bf16) = A[N,K] x W[K,M](bf16) ----------------
// AT = ushort (bf16 rows) or float (f32 rows, converted to bf16 in-register).
// mode: -1 = always run; 0 = run iff flags[0]==0; 1 = run iff flags[0]==1.

template<typename AT>
__device__ __forceinline__ bf16x8 ld_afrag(const AT* p);
template<>
__device__ __forceinline__ bf16x8 ld_afrag<unsigned short>(const unsigned short* p) {
    return *(const bf16x8*)p;
}
template<>
__device__ __forceinline__ bf16x8 ld_afrag<float>(const float* p) {
    float4 a = *(const float4*)p;
    float4 b = *(const float4*)(p + 4);
    bf16x8 r;
    r[0] = (short)f2bf(a.x); r[1] = (short)f2bf(a.y);
    r[2] = (short)f2bf(a.z); r[3] = (short)f2bf(a.w);
    r[4] = (short)f2bf(b.x); r[5] = (short)f2bf(b.y);
    r[6] = (short)f2bf(b.z); r[7] = (short)f2bf(b.w);
    return r;
}

template<int K, int M, typename AT>
__launch_bounds__(256)
__global__ void mm_mfma_kernel(const AT* __restrict__ A,
                               const unsigned short* __restrict__ WT,
                               unsigned short* __restrict__ C, int N,
                               const int* __restrict__ flags, int mode) {
    if (mode >= 0 && flags[0] != mode) return;
    __shared__ unsigned short Ws[M][K + 8];
    int tid = threadIdx.x;
    for (int idx = tid; idx < M * K / 8; idx += 256) {
        int r = idx / (K / 8), c8 = idx % (K / 8);
        *(uint4*)&Ws[r][c8 * 8] = *(const uint4*)&WT[r * K + c8 * 8];
    }
    __syncthreads();
    int w = tid >> 6, lane = tid & 63;
    int m = lane & 15, q = lane >> 4;
    int row_a = blockIdx.x * 64 + w * 16 + m;
    if (row_a >= N) row_a = N - 1;              // clamp; garbage rows masked at store
    const AT* arow = A + (size_t)row_a * K;
    f32x4 acc[M / 16];
    #pragma unroll
    for (int t = 0; t < M / 16; ++t) acc[t] = (f32x4){0.f, 0.f, 0.f, 0.f};
    #pragma unroll
    for (int ks = 0; ks < K / 32; ++ks) {
        int k0 = ks * 32 + q * 8;
        bf16x8 a = ld_afrag<AT>(arow + k0);
        #pragma unroll
        for (int t = 0; t < M / 16; ++t) {
            bf16x8 b = *(const bf16x8*)&Ws[t * 16 + m][k0];
            acc[t] = __builtin_amdgcn_mfma_f32_16x16x32_bf16(a, b, acc[t], 0, 0, 0);
        }
    }
    int rbase = blockIdx.x * 64 + w * 16 + q * 4;
    #pragma unroll
    for (int reg = 0; reg < 4; ++reg) {
        int row = rbase + reg;
        if (row < N) {
            #pragma unroll
            for (int t = 0; t < M / 16; ++t)
                C[(size_t)row * M + t * 16 + m] = f2bf(acc[t][reg]);
        }
    }
}

// ---------------- aggregation + optional ReLU/LN ----------------
// 4 NODES PER WAVE: wave = 4 independent 16-lane groups, one node each.

template<int VPL>
__device__ __forceinline__ void gacc1(float* acc, const unsigned short* r, float n) {
    if constexpr (VPL == 8) {
        uint4 u = *(const uint4*)r;
        acc[0] += bf2f(u.x & 0xffffu) * n; acc[1] += bf2f(u.x >> 16) * n;
        acc[2] += bf2f(u.y & 0xffffu) * n; acc[3] += bf2f(u.y >> 16) * n;
        acc[4] += bf2f(u.z & 0xffffu) * n; acc[5] += bf2f(u.z >> 16) * n;
        acc[6] += bf2f(u.w & 0xffffu) * n; acc[7] += bf2f(u.w >> 16) * n;
    } else {
        uint2 u = *(const uint2*)r;
        acc[0] += bf2f(u.x & 0xffffu) * n; acc[1] += bf2f(u.x >> 16) * n;
        acc[2] += bf2f(u.y & 0xffffu) * n; acc[3] += bf2f(u.y >> 16) * n;
    }
}

template<int VPL>
__device__ __forceinline__ void gacc4(float* acc,
                                      const unsigned short* r0, float n0,
                                      const unsigned short* r1, float n1,
                                      const unsigned short* r2, float n2,
                                      const unsigned short* r3, float n3) {
    if constexpr (VPL == 8) {
        uint4 u0 = *(const uint4*)r0;
        uint4 u1 = *(const uint4*)r1;
        uint4 u2 = *(const uint4*)r2;
        uint4 u3 = *(const uint4*)r3;
        acc[0] += bf2f(u0.x & 0xffffu) * n0 + bf2f(u1.x & 0xffffu) * n1
                + bf2f(u2.x & 0xffffu) * n2 + bf2f(u3.x & 0xffffu) * n3;
        acc[1] += bf2f(u0.x >> 16) * n0 + bf2f(u1.x >> 16) * n1
                + bf2f(u2.x >> 16) * n2 + bf2f(u3.x >> 16) * n3;
        acc[2] += bf2f(u0.y & 0xffffu) * n0 + bf2f(u1.y & 0xffffu) * n1
                + bf2f(u2.y & 0xffffu) * n2 + bf2f(u3.y & 0xffffu) * n3;
        acc[3] += bf2f(u0.y >> 16) * n0 + bf2f(u1.y >> 16) * n1
                + bf2f(u2.y >> 16) * n2 + bf2f(u3.y >> 16) * n3;
        acc[4] += bf2f(u0.z & 0xffffu) * n0 + bf2f(u1.z & 0xffffu) * n1
                + bf2f(u2.z & 0xffffu) * n2 + bf2f(u3.z & 0xffffu) * n3;
        acc[5] += bf2f(u0.z >> 16) * n0 + bf2f(u1.z >> 16) * n1
                + bf2f(u2.z >> 16) * n2 + bf2f(u3.z >> 16) * n3;
        acc[6] += bf2f(u0.w & 0xffffu) * n0 + bf2f(u1.w & 0xffffu) * n1
                + bf2f(u2.w & 0xffffu) * n2 + bf2f(u3.w & 0xffffu) * n3;
        acc[7] += bf2f(u0.w >> 16) * n0 + bf2f(u1.w >> 16) * n1
                + bf2f(u2.w >> 16) * n2 + bf2f(u3.w >> 16) * n3;
    } else {
        uint2 u0 = *(const uint2*)r0;
        uint2 u1 = *(const uint2*)r1;
        uint2 u2 = *(const uint2*)r2;
        uint2 u3 = *(const uint2*)r3;
        acc[0] += bf2f(u0.x & 0xffffu) * n0 + bf2f(u1.x & 0xffffu) * n1
                + bf2f(u2.x & 0xffffu) * n2 + bf2f(u3.x & 0xffffu) * n3;
        acc[1] += bf2f(u0.x >> 16) * n0 + bf2f(u1.x >> 16) * n1
                + bf2f(u2.x >> 16) * n2 + bf2f(u3.x >> 16) * n3;
        acc[2] += bf2f(u0.y & 0xffffu) * n0 + bf2f(u1.y & 0xffffu) * n1
                + bf2f(u2.y & 0xffffu) * n2 + bf2f(u3.y & 0xffffu) * n3;
        acc[3] += bf2f(u0.y >> 16) * n0 + bf2f(u1.y >> 16) * n1
                + bf2f(u2.y >> 16) * n2 + bf2f(u3.y >> 16) * n3;
    }
}

template<int H, bool RELU_LN, bool EMB>
__launch_bounds__(256)
__global__ void agg_kernel(const unsigned short* __restrict__ h,
                           const int* __restrict__ indptr,
                           const int2* __restrict__ csr_sn,
                           const float* __restrict__ dinv,
                           const float* __restrict__ bias,
                           const float* __restrict__ gamma,
                           const float* __restrict__ beta,
                           unsigned short* __restrict__ out,
                           void* __restrict__ out_emb,
                           int N, const int* __restrict__ flags) {
    constexpr int VPL = H / 16;                 // 8 (H=128), 4 (H=64)
    __shared__ int2 lsn[4][4][16];              // [wave][group][idx]
    int w = threadIdx.x >> 6;
    int lane = threadIdx.x & 63;
    int g = lane >> 4;                          // group = node within wave
    int idx = lane & 15;
    int node = blockIdx.x * 16 + w * 4 + g;
    bool active = node < N;
    int nd = active ? node : N - 1;             // clamp; inactive groups never store
    float di = dinv[nd];
    int c0 = idx * VPL;
    float acc[VPL];
    #pragma unroll
    for (int v = 0; v < VPL; ++v) acc[v] = 0.f;
    // self loop (full group covers the row once)
    gacc1<VPL>(acc, h + (size_t)nd * H + c0, di * di);
    int beg = indptr[nd], end = indptr[nd + 1];
    for (int base = beg; base < end; base += 16) {
        int m = end - base; if (m > 16) m = 16;
        if (idx < m) lsn[w][g][idx] = csr_sn[base + idx];
        // same-wave LDS write->read: ordered, no barrier
        int j = 0;
        for (; j + 3 < m; j += 4) {
            int2 e0 = lsn[w][g][j],     e1 = lsn[w][g][j + 1];
            int2 e2 = lsn[w][g][j + 2], e3 = lsn[w][g][j + 3];
            gacc4<VPL>(acc,
                       h + (size_t)e0.x * H + c0, __int_as_float(e0.y),
                       h + (size_t)e1.x * H + c0, __int_as_float(e1.y),
                       h + (size_t)e2.x * H + c0, __int_as_float(e2.y),
                       h + (size_t)e3.x * H + c0, __int_as_float(e3.y));
        }
        for (; j < m; ++j) {
            int2 e = lsn[w][g][j];
            gacc1<VPL>(acc, h + (size_t)e.x * H + c0, __int_as_float(e.y));
        }
    }
    #pragma unroll
    for (int v = 0; v < VPL; ++v) acc[v] += bias[c0 + v];
    if constexpr (RELU_LN) {
        #pragma unroll
        for (int v = 0; v < VPL; ++v) acc[v] = fmaxf(acc[v], 0.f);
        float s = 0.f, sq = 0.f;
        #pragma unroll
        for (int v = 0; v < VPL; ++v) { s += acc[v]; sq += acc[v] * acc[v]; }
        #pragma unroll
        for (int off = 8; off >= 1; off >>= 1) {   // stays inside the 16-lane group
            s += __shfl_xor(s, off, 64);
            sq += __shfl_xor(sq, off, 64);
        }
        float mu = s * (1.0f / H);
        float var = fmaxf(sq * (1.0f / H) - mu * mu, 0.f);
        float inv = 1.0f / sqrtf(var + 1e-5f);
        #pragma unroll
        for (int v = 0; v < VPL; ++v)
            acc[v] = (acc[v] - mu) * inv * gamma[c0 + v] + beta[c0 + v];
    }
    if (active) {
        unsigned short* orow = out + (size_t)node * H + c0;
        if constexpr (VPL == 8) {
            uint4 p;
            p.x = packbf(acc[0], acc[1]); p.y = packbf(acc[2], acc[3]);
            p.z = packbf(acc[4], acc[5]); p.w = packbf(acc[6], acc[7]);
            *(uint4*)orow = p;
        } else {
            uint2 p; p.x = packbf(acc[0], acc[1]); p.y = packbf(acc[2], acc[3]);
            *(uint2*)orow = p;
        }
        if constexpr (EMB) {
            if (flags[0]) {
                float* o = (float*)out_emb + (size_t)node * H + c0;
                #pragma unroll
                for (int v4 = 0; v4 < VPL / 4; ++v4)
                    *(float4*)(o + v4 * 4) = make_float4(acc[v4 * 4], acc[v4 * 4 + 1],
                                                         acc[v4 * 4 + 2], acc[v4 * 4 + 3]);
            } else {
                unsigned short* o = (unsigned short*)out_emb + (size_t)node * H + c0;
                #pragma unroll
                for (int v2 = 0; v2 < VPL / 2; ++v2)
                    ((unsigned int*)o)[v2] = packbf(acc[v2 * 2], acc[v2 * 2 + 1]);
            }
        }
    }
}

// ---------------- post-mp head: LDS-tiled GEMM + log_softmax ----------------

__launch_bounds__(256)
__global__ void head_kernel(const unsigned short* __restrict__ emb,
                            const float* __restrict__ Wp1,
                            const float* __restrict__ bp1,
                            const float* __restrict__ Wp2,
                            const float* __restrict__ bp2,
                            void* __restrict__ d_out, int N,
                            const int* __restrict__ flags) {
    __shared__ float Est[64][68];     // [k][row], relu'd
    __shared__ float W1s[64][64];     // [k][c]
    __shared__ float Tst[64][68];     // [c][row]
    __shared__ float W2s[64][OUTD];   // [c][o]
    __shared__ float b1s[64];
    __shared__ float b2s[OUTD];
    int tid = threadIdx.x;
    int row0 = blockIdx.x * 64;
    for (int i = tid; i < 64 * 64; i += 256) W1s[i >> 6][i & 63] = Wp1[i];
    for (int i = tid; i < 64 * OUTD; i += 256) W2s[i / OUTD][i % OUTD] = Wp2[i];
    if (tid < 64) b1s[tid] = bp1[tid];
    if (tid < OUTD) b2s[tid] = bp2[tid];
    for (int i = tid; i < 64 * 32; i += 256) {
        int r = i >> 5, kk = i & 31;
        int row = row0 + r;
        unsigned int u = (row < N) ? *(const unsigned int*)&emb[(size_t)row * 64 + kk * 2] : 0u;
        Est[kk * 2][r]     = fmaxf(bf2f(u & 0xffffu), 0.f);
        Est[kk * 2 + 1][r] = fmaxf(bf2f(u >> 16), 0.f);
    }
    __syncthreads();
    // phase 1
    {
        int rg = tid >> 4, cg = tid & 15;
        int r = rg * 4, c = cg * 4;
        float acc[4][4];
        #pragma unroll
        for (int i = 0; i < 4; ++i)
            #pragma unroll
            for (int jj = 0; jj < 4; ++jj) acc[i][jj] = b1s[c + jj];
        #pragma unroll 4
        for (int k = 0; k < 64; ++k) {
            float4 a = *(const float4*)&Est[k][r];
            float4 wv = *(const float4*)&W1s[k][c];
            acc[0][0] += a.x * wv.x; acc[0][1] += a.x * wv.y; acc[0][2] += a.x * wv.z; acc[0][3] += a.x * wv.w;
            acc[1][0] += a.y * wv.x; acc[1][1] += a.y * wv.y; acc[1][2] += a.y * wv.z; acc[1][3] += a.y * wv.w;
            acc[2][0] += a.z * wv.x; acc[2][1] += a.z * wv.y; acc[2][2] += a.z * wv.z; acc[2][3] += a.z * wv.w;
            acc[3][0] += a.w * wv.x; acc[3][1] += a.w * wv.y; acc[3][2] += a.w * wv.z; acc[3][3] += a.w * wv.w;
        }
        #pragma unroll
        for (int i = 0; i < 4; ++i)
            #pragma unroll
            for (int jj = 0; jj < 4; ++jj) Tst[c + jj][r + i] = acc[i][jj];
    }
    __syncthreads();
    // phase 2 + 3
    int row = tid >> 2, tc = tid & 3, o0 = tc * 10;
    int node = row0 + row;
    float u[10];
    #pragma unroll
    for (int o = 0; o < 10; ++o) u[o] = b2s[o0 + o];
    for (int c2 = 0; c2 < 64; ++c2) {
        float tv = Tst[c2][row];
        const float2* wp = (const float2*)&W2s[c2][o0];
        #pragma unroll
        for (int o2 = 0; o2 < 5; ++o2) {
            float2 wv = wp[o2];
            u[o2 * 2]     += tv * wv.x;
            u[o2 * 2 + 1] += tv * wv.y;
        }
    }
    float mx = u[0];
    #pragma unroll
    for (int o = 1; o < 10; ++o) mx = fmaxf(mx, u[o]);
    mx = fmaxf(mx, __shfl_xor(mx, 1, 64));
    mx = fmaxf(mx, __shfl_xor(mx, 2, 64));
    float sum = 0.f;
    #pragma unroll
    for (int o = 0; o < 10; ++o) sum += __expf(u[o] - mx);
    sum += __shfl_xor(sum, 1, 64);
    sum += __shfl_xor(sum, 2, 64);
    float lse = mx + __logf(sum);
    if (node < N) {
        if (flags[0]) {
            float* base = (float*)d_out + (size_t)N * HID2;
            float* op = base + (size_t)node * OUTD + o0;
            #pragma unroll
            for (int o = 0; o < 10; ++o) op[o] = u[o] - lse;
        } else {
            unsigned short* base = (unsigned short*)d_out + (size_t)N * HID2;
            unsigned int* op = (unsigned int*)(base + (size_t)node * OUTD + o0);
            #pragma unroll
            for (int o2 = 0; o2 < 5; ++o2)
                op[o2] = packbf(u[o2 * 2] - lse, u[o2 * 2 + 1] - lse);
        }
    }
}

// ---------------- launch ----------------

extern "C" void kernel_launch(void* const* d_in, const int* in_sizes, int n_in,
                              void* d_out, int out_size, void* d_ws, size_t ws_size,
                              hipStream_t stream) {
    const unsigned short* xu = (const unsigned short*)d_in[0];
    const float*          xf = (const float*)d_in[0];
    const int*            ei = (const int*)d_in[1];

    const int N = in_sizes[0] / DIN;   // 50000
    const int E = in_sizes[1] / 2;     // 800000

    size_t off = 0;
    auto take = [&](size_t bytes) {
        size_t cur = off;
        off += (bytes + 255) & ~(size_t)255;
        return cur;
    };
    char* ws = (char*)d_ws;
    int*   flags   = (int*)  (ws + take(256));
    int*   cnt     = (int*)  (ws + take((size_t)N * 4));
    float* dinv    = (float*)(ws + take((size_t)N * 4));
    int*   indptr  = (int*)  (ws + take((size_t)(N + 1) * 4));
    int*   pos     = (int*)  (ws + take((size_t)E * 4));
    int2*  csr_sn  = (int2*) (ws + take((size_t)E * 8));
    int*   bsum    = (int*)  (ws + take(((size_t)N / 256 + 2) * 4));
    int*   bbase   = (int*)  (ws + take(((size_t)N / 256 + 2) * 4));
    unsigned short* wbf = (unsigned short*)(ws + take(32768 * 2));
    float*          wf  = (float*)         (ws + take(8192 * 4));
    unsigned short* hbuf = (unsigned short*)(ws + take((size_t)N * DIN * 2));
    unsigned short* abuf = (unsigned short*)(ws + take((size_t)N * DIN * 2));
    (void)ws_size; (void)n_in; (void)out_size;

    const int TB = 256;
    dim3 blk(TB);
    const int NB = (N + 255) / 256;

    pre_kernel<<<dim3(NB), blk, 0, stream>>>(xu, ei, flags, cnt, N);
    pos_kernel<<<dim3((E + 1023) / 1024), blk, 0, stream>>>(ei, cnt, pos, E, N, flags);
    bsum_kernel<<<dim3(NB), blk, 0, stream>>>(cnt, bsum, N);
    bscan_kernel<<<dim3(1), blk, 0, stream>>>(bsum, bbase, indptr, NB, N);
    emit_kernel<<<dim3(NB), blk, 0, stream>>>(cnt, bbase, indptr, dinv, N);
    scatter_kernel<<<dim3((E + 1023) / 1024), blk, 0, stream>>>(ei, indptr, pos, dinv, csr_sn, E, N, flags);

    // weight conversion: W1/W2/W3 -> bf16 arena TRANSPOSED; rest -> f32 arena
    WCvt w;
    int bfoff = 0, foff = 0;
    int offs[14];
    const int wcols[14] = {HID1, 0, HID2, 0, HID2, 0, 0, 0, 0, 0, 0, 0, 0, 0};
    for (int a = 0; a < 14; ++a) {
        int idx = a + 2;
        w.p[a] = d_in[idx];
        w.sz[a] = in_sizes[idx];
        int tobf = (idx == 2 || idx == 4 || idx == 6) ? 1 : 0;
        w.tobf[a] = tobf;
        w.cols[a] = tobf ? wcols[a] : 1;
        if (tobf) { w.off[a] = bfoff; bfoff += in_sizes[idx]; }
        else      { w.off[a] = foff;  foff  += in_sizes[idx]; }
        offs[a] = w.off[a];
    }
    wcvt_kernel<<<dim3(64), blk, 0, stream>>>(w, wbf, wf, flags);

    unsigned short* W1t = wbf + offs[0];   // [128][128] transposed
    unsigned short* W2t = wbf + offs[2];   // [64][128] transposed
    unsigned short* W3t = wbf + offs[4];   // [64][64] transposed
    float* b1f  = wf + offs[1];
    float* b2f  = wf + offs[3];
    float* b3f  = wf + offs[5];
    float* g1f  = wf + offs[6];
    float* be1f = wf + offs[7];
    float* g2f  = wf + offs[8];
    float* be2f = wf + offs[9];
    float* Wp1f = wf + offs[10];
    float* bp1f = wf + offs[11];
    float* Wp2f = wf + offs[12];
    float* bp2f = wf + offs[13];

    const int MMG = (N + 63) / 64;
    const int AGG = (N + 15) / 16;

    // layer 1: dual-dtype x, in-register f32->bf16 conversion; one variant early-exits
    mm_mfma_kernel<DIN, HID1, unsigned short><<<dim3(MMG), blk, 0, stream>>>(
        xu, W1t, hbuf, N, flags, 0);
    mm_mfma_kernel<DIN, HID1, float><<<dim3(MMG), blk, 0, stream>>>(
        xf, W1t, hbuf, N, flags, 1);
    agg_kernel<HID1, true, false><<<dim3(AGG), blk, 0, stream>>>(
        hbuf, indptr, csr_sn, dinv, b1f, g1f, be1f, abuf, nullptr, N, flags);

    // layer 2
    mm_mfma_kernel<HID1, HID2, unsigned short><<<dim3(MMG), blk, 0, stream>>>(
        abuf, W2t, hbuf, N, flags, -1);
    agg_kernel<HID2, true, false><<<dim3(AGG), blk, 0, stream>>>(
        hbuf, indptr, csr_sn, dinv, b2f, g2f, be2f, abuf, nullptr, N, flags);

    // layer 3 -> emb
    mm_mfma_kernel<HID2, HID2, unsigned short><<<dim3(MMG), blk, 0, stream>>>(
        abuf, W3t, hbuf, N, flags, -1);
    agg_kernel<HID2, false, true><<<dim3(AGG), blk, 0, stream>>>(
        hbuf, indptr, csr_sn, dinv, b3f, nullptr, nullptr, abuf, d_out, N, flags);

    // head
    head_kernel<<<dim3((N + 63) / 64), blk, 0, stream>>>(
        abuf, Wp1f, bp1f, Wp2f, bp2f, d_out, N, flags);
}